// Round 7
// baseline (470.947 us; speedup 1.0000x reference)
//
#include <hip/hip_runtime.h>
#include <hip/hip_bf16.h>

// LSS voxel pooling: coarse-bucket counting sort + LDS-atomic gather.
// B=2, N=6, D=112, H=16, W=44, C=80, BEV 128x128.
// Round-4 lesson: exact per-voxel sort paid 8x write amplification on random
// 8B scatters (58 MB HBM writes). Coarse 512-bucket sort with block-aggregated
// clustered writes + per-bucket LDS accumulation removes it.

constexpr int B = 2, N = 6, D = 112, H = 16, W = 44, C = 80;
constexpr int HW = H * W;            // 704 (= 11*64)
constexpr int NPIX = B * N * HW;     // 8448
constexpr int NV = 128 * 128;        // 16384
constexpr int PTS = NPIX * D;        // 946176
constexpr int DHW = D * HW;          // 78848
constexpr int NBKT = 512;            // buckets over flat bins (64 bins each)
constexpr int CAP = 2816;            // per-bucket capacity (mean 1848, +22 sigma)

__global__ __launch_bounds__(NBKT) void init_cursor_kernel(
    int* __restrict__ cursor) {
  cursor[threadIdx.x] = threadIdx.x * CAP;
}

// ---- fused: ctx transpose + softmax + bucketed scatter ----
// block = 64 consecutive pixels of one camera (bn), 256 threads.
// thread (q,l): d-group q (28 bins), pixel lane l.
__global__ __launch_bounds__(256) void fused_scatter_kernel(
    const float* __restrict__ logits, const float* __restrict__ ctx,
    const int* __restrict__ gidx, float* __restrict__ ctxT,
    int* __restrict__ cursor, uint2* __restrict__ sorted) {
  const int t = threadIdx.x;
  const int pix0 = blockIdx.x * 64;
  const int bn = pix0 / HW;
  const int hw0 = pix0 - bn * HW;
  const int b = bn / N;

  __shared__ float tile[C][65];
  __shared__ float redm[4][64], reds[4][64];
  __shared__ int hist[NBKT], sbase[NBKT], lcur[NBKT];

  // --- ctx transpose: load strided tile ---
  const float* src = ctx + (size_t)bn * C * HW + hw0;
#pragma unroll
  for (int it = 0; it < (C * 64) / 256; ++it) {
    const int idx = it * 256 + t;
    const int c = idx >> 6;
    const int i = idx & 63;
    tile[c][i] = src[(size_t)c * HW + i];
  }
  hist[t] = 0;
  hist[t + 256] = 0;
  __syncthreads();
  {
    float* dst = ctxT + (size_t)pix0 * C;
#pragma unroll
    for (int it = 0; it < (C * 64) / 256; ++it) {
      const int j = it * 256 + t;
      const int pl = j / C;
      const int c = j - pl * C;
      dst[j] = tile[c][pl];   // coalesced; tile read conflict-free (stride 65)
    }
  }

  // --- softmax over D (28 logits per thread, in registers) ---
  const int l = t & 63;
  const int q = t >> 6;
  const int hw = hw0 + l;
  const int pix = pix0 + l;
  const int d0 = q * 28;
  const float* lg = logits + (size_t)bn * DHW + hw;

  float x[28];
  float m = -3.0e38f;
#pragma unroll
  for (int j = 0; j < 28; ++j) {
    x[j] = lg[(size_t)(d0 + j) * HW];   // coalesced across l
    m = fmaxf(m, x[j]);
  }
  redm[q][l] = m;
  __syncthreads();
  m = fmaxf(fmaxf(redm[0][l], redm[1][l]), fmaxf(redm[2][l], redm[3][l]));
  float s = 0.0f;
#pragma unroll
  for (int j = 0; j < 28; ++j) {
    x[j] = __expf(x[j] - m);
    s += x[j];
  }
  reds[q][l] = s;
  __syncthreads();
  const float inv =
      1.0f / (reds[0][l] + reds[1][l] + reds[2][l] + reds[3][l]);

  // --- build records: w0 = pix(14b) | flatbin(15b)<<16 ---
  const int* gi = gidx + (size_t)bn * DHW + hw;
  unsigned w0[28];
#pragma unroll
  for (int j = 0; j < 28; ++j) {
    const int fb = b * NV + gi[(size_t)(d0 + j) * HW];   // coalesced
    w0[j] = (unsigned)pix | ((unsigned)fb << 16);
    x[j] *= inv;
  }

  // --- block-local bucket histogram ---
#pragma unroll
  for (int j = 0; j < 28; ++j) atomicAdd(&hist[w0[j] >> 22], 1);
  __syncthreads();

  // --- reserve contiguous per-bucket ranges (<=512 global atomics/block) ---
  for (int k = t; k < NBKT; k += 256) {
    const int c_ = hist[k];
    sbase[k] = c_ ? atomicAdd(&cursor[k], c_) : 0;
    lcur[k] = 0;
  }
  __syncthreads();

  // --- write records clustered per bucket ---
#pragma unroll
  for (int j = 0; j < 28; ++j) {
    const int bk = w0[j] >> 22;
    const int off = atomicAdd(&lcur[bk], 1);
    const int pos = sbase[bk] + off;
    if (pos < (bk + 1) * CAP)   // statistically unreachable guard
      sorted[pos] = make_uint2(w0[j], __float_as_uint(x[j]));
  }
}

// ---- bucket gather: one block per bucket, LDS f32-atomic accumulation ----
// block g: batch b=g>>8, voxels (g&255)*64 .. +64. 512 threads = 8 waves.
__global__ __launch_bounds__(512) void bucket_gather_kernel(
    const float* __restrict__ ctxT, const uint2* __restrict__ sorted,
    const int* __restrict__ cursor, float* __restrict__ out) {
  const int t = threadIdx.x;
  const int g = blockIdx.x;
  const int b = g >> 8;
  const int vox0 = (g & 255) * 64;

  __shared__ float tile[64][80];   // 20 KB
  float* tf = &tile[0][0];
#pragma unroll
  for (int i = 0; i < 10; ++i) tf[i * 512 + t] = 0.0f;
  __syncthreads();

  int cnt = cursor[g] - g * CAP;
  if (cnt > CAP) cnt = CAP;
  const uint2* rec = sorted + (size_t)g * CAP;
  const int w = t >> 6;
  const int l = t & 63;

  const int r0 = (cnt * w) >> 3;
  const int r1 = (cnt * (w + 1)) >> 3;
  int r = r0;
  for (; r + 4 <= r1; r += 4) {
    const uint2 ra = rec[r + 0];
    const uint2 rb = rec[r + 1];
    const uint2 rc = rec[r + 2];
    const uint2 rd = rec[r + 3];
    const float* wa = ctxT + (size_t)(ra.x & 0xFFFFu) * C;
    const float* wb = ctxT + (size_t)(rb.x & 0xFFFFu) * C;
    const float* wc = ctxT + (size_t)(rc.x & 0xFFFFu) * C;
    const float* wd = ctxT + (size_t)(rd.x & 0xFFFFu) * C;
    const float pa = __uint_as_float(ra.y);
    const float pb = __uint_as_float(rb.y);
    const float pc = __uint_as_float(rc.y);
    const float pd = __uint_as_float(rd.y);
    const float va = wa[l], vb = wb[l], vc = wc[l], vd = wd[l];
    atomicAdd(&tile[(ra.x >> 16) & 63][l], pa * va);
    atomicAdd(&tile[(rb.x >> 16) & 63][l], pb * vb);
    atomicAdd(&tile[(rc.x >> 16) & 63][l], pc * vc);
    atomicAdd(&tile[(rd.x >> 16) & 63][l], pd * vd);
    if (l < 16) {
      const float ua = wa[64 + l], ub = wb[64 + l];
      const float uc = wc[64 + l], ud = wd[64 + l];
      atomicAdd(&tile[(ra.x >> 16) & 63][64 + l], pa * ua);
      atomicAdd(&tile[(rb.x >> 16) & 63][64 + l], pb * ub);
      atomicAdd(&tile[(rc.x >> 16) & 63][64 + l], pc * uc);
      atomicAdd(&tile[(rd.x >> 16) & 63][64 + l], pd * ud);
    }
  }
  for (; r < r1; ++r) {
    const uint2 ra = rec[r];
    const float* wa = ctxT + (size_t)(ra.x & 0xFFFFu) * C;
    const float pa = __uint_as_float(ra.y);
    atomicAdd(&tile[(ra.x >> 16) & 63][l], pa * wa[l]);
    if (l < 16) atomicAdd(&tile[(ra.x >> 16) & 63][64 + l], pa * wa[64 + l]);
  }
  __syncthreads();

  // write out [b][c][vox0..vox0+64), coalesced 256B per wave-instr
  const size_t ob = (size_t)b * C * NV + vox0;
#pragma unroll
  for (int i = 0; i < 10; ++i) {
    const int idx = i * 512 + t;
    const int c = idx >> 6;
    const int v = idx & 63;
    out[ob + (size_t)c * NV + v] = tile[v][c];
  }
}

// ---- fallback: direct channel-major atomics (out must be zeroed) ----
__global__ __launch_bounds__(256) void lift_splat_direct_kernel(
    const float* __restrict__ logits, const float* __restrict__ ctx,
    const int* __restrict__ gidx, float* __restrict__ out) {
  const int t = threadIdx.x;
  const int pix = blockIdx.x;
  const int hw = pix % HW;
  const int bn = pix / HW;
  const int b = bn / N;

  const float* lg = logits + (size_t)bn * DHW + hw;
  const int* gi = gidx + (size_t)bn * DHW + hw;
  const float* cx = ctx + (size_t)bn * (C * HW) + hw;

  __shared__ float s_prob[D];
  __shared__ float s_ctx[C];
  __shared__ int s_idx[D];
  __shared__ float red[256];

  float v = -3.0e38f;
  if (t < D) {
    v = lg[(size_t)t * HW];
    s_idx[t] = gi[(size_t)t * HW];
  }
  if (t < C) s_ctx[t] = cx[(size_t)t * HW];

  red[t] = v;
  __syncthreads();
#pragma unroll
  for (int s = 128; s >= 1; s >>= 1) {
    if (t < s) red[t] = fmaxf(red[t], red[t + s]);
    __syncthreads();
  }
  const float m = red[0];
  __syncthreads();

  const float e = (t < D) ? __expf(v - m) : 0.0f;
  red[t] = e;
  __syncthreads();
#pragma unroll
  for (int s = 128; s >= 1; s >>= 1) {
    if (t < s) red[t] += red[t + s];
    __syncthreads();
  }
  const float inv = 1.0f / red[0];
  if (t < D) s_prob[t] = e * inv;
  __syncthreads();

  for (int f = t; f < D * C; f += 256) {
    const int d = f / C;
    const int c = f - d * C;
    atomicAdd(&out[((size_t)(b * C + c)) * NV + s_idx[d]],
              s_prob[d] * s_ctx[c]);
  }
}

extern "C" void kernel_launch(void* const* d_in, const int* in_sizes, int n_in,
                              void* d_out, int out_size, void* d_ws,
                              size_t ws_size, hipStream_t stream) {
  const float* logits = (const float*)d_in[0];
  const float* ctx = (const float*)d_in[1];
  const int* gidx = (const int*)d_in[2];
  float* out = (float*)d_out;

  size_t off = 0;
  uint2* sorted = (uint2*)((char*)d_ws + off);
  off += (size_t)NBKT * CAP * sizeof(uint2);             // 11,534,336
  float* ctxT = (float*)((char*)d_ws + off);
  off += (size_t)NPIX * C * sizeof(float);               //  2,703,360
  int* cursor = (int*)((char*)d_ws + off);
  off += (size_t)NBKT * sizeof(int);                     // total ~14.24 MB

  if (ws_size >= off) {
    init_cursor_kernel<<<1, NBKT, 0, stream>>>(cursor);
    fused_scatter_kernel<<<NPIX / 64, 256, 0, stream>>>(logits, ctx, gidx,
                                                        ctxT, cursor, sorted);
    bucket_gather_kernel<<<NBKT, 512, 0, stream>>>(ctxT, sorted, cursor, out);
  } else {
    (void)hipMemsetAsync(d_out, 0, (size_t)out_size * sizeof(float), stream);
    lift_splat_direct_kernel<<<NPIX, 256, 0, stream>>>(logits, ctx, gidx, out);
  }
}

// Round 8
// 113.352 us; speedup vs baseline: 4.1547x; 4.1547x over previous
//
#include <hip/hip_runtime.h>
#include <hip/hip_bf16.h>

// LSS voxel pooling: coarse-bucket counting sort + in-LDS voxel sort +
// register-accumulate gather. NO bulk LDS atomics (round-7 lesson: LDS
// f32 atomicAdd ~3cy/lane serialized -> 399us; register acc is the way).
// B=2, N=6, D=112, H=16, W=44, C=80, BEV 128x128.

constexpr int B = 2, N = 6, D = 112, H = 16, W = 44, C = 80;
constexpr int HW = H * W;            // 704 (= 11*64)
constexpr int NPIX = B * N * HW;     // 8448
constexpr int NV = 128 * 128;        // 16384
constexpr int PTS = NPIX * D;        // 946176
constexpr int DHW = D * HW;          // 78848
constexpr int NBKT = 512;            // buckets of 64 voxel-bins each
constexpr int CAP = 2816;            // per-bucket capacity (mean 1848, +22 sigma)

__global__ __launch_bounds__(NBKT) void init_cursor_kernel(
    int* __restrict__ cursor) {
  cursor[threadIdx.x] = threadIdx.x * CAP;
}

// ---- fused: ctx transpose + softmax + bucketed scatter ----
// block = 64 consecutive pixels of one camera (bn), 256 threads.
__global__ __launch_bounds__(256) void fused_scatter_kernel(
    const float* __restrict__ logits, const float* __restrict__ ctx,
    const int* __restrict__ gidx, float* __restrict__ ctxT,
    int* __restrict__ cursor, uint2* __restrict__ sorted) {
  const int t = threadIdx.x;
  const int pix0 = blockIdx.x * 64;
  const int bn = pix0 / HW;
  const int hw0 = pix0 - bn * HW;
  const int b = bn / N;

  __shared__ float tile[C][65];
  __shared__ float redm[4][64], reds[4][64];
  __shared__ int hist[NBKT], sbase[NBKT];

  // --- ctx transpose ---
  const float* src = ctx + (size_t)bn * C * HW + hw0;
#pragma unroll
  for (int it = 0; it < (C * 64) / 256; ++it) {
    const int idx = it * 256 + t;
    const int c = idx >> 6;
    const int i = idx & 63;
    tile[c][i] = src[(size_t)c * HW + i];
  }
  hist[t] = 0;
  hist[t + 256] = 0;
  __syncthreads();
  {
    float* dst = ctxT + (size_t)pix0 * C;
#pragma unroll
    for (int it = 0; it < (C * 64) / 256; ++it) {
      const int j = it * 256 + t;
      const int pl = j / C;
      const int c = j - pl * C;
      dst[j] = tile[c][pl];
    }
  }

  // --- softmax over D (28 logits/thread in registers) ---
  const int l = t & 63;
  const int q = t >> 6;
  const int hw = hw0 + l;
  const int pix = pix0 + l;
  const int d0 = q * 28;
  const float* lg = logits + (size_t)bn * DHW + hw;

  float x[28];
  float m = -3.0e38f;
#pragma unroll
  for (int j = 0; j < 28; ++j) {
    x[j] = lg[(size_t)(d0 + j) * HW];
    m = fmaxf(m, x[j]);
  }
  redm[q][l] = m;
  __syncthreads();
  m = fmaxf(fmaxf(redm[0][l], redm[1][l]), fmaxf(redm[2][l], redm[3][l]));
  float s = 0.0f;
#pragma unroll
  for (int j = 0; j < 28; ++j) {
    x[j] = __expf(x[j] - m);
    s += x[j];
  }
  reds[q][l] = s;
  __syncthreads();
  const float inv =
      1.0f / (reds[0][l] + reds[1][l] + reds[2][l] + reds[3][l]);

  // --- records: w0 = pix(low16) | flatbin<<16; rank via returning atomic ---
  const int* gi = gidx + (size_t)bn * DHW + hw;
  unsigned w0[28];
  int rank[28];
#pragma unroll
  for (int j = 0; j < 28; ++j) {
    const int fb = b * NV + gi[(size_t)(d0 + j) * HW];
    w0[j] = (unsigned)pix | ((unsigned)fb << 16);
    x[j] *= inv;
    rank[j] = atomicAdd(&hist[w0[j] >> 22], 1);  // block-bucket rank
  }
  __syncthreads();

  // --- reserve per-bucket ranges (<=512 global atomics/block) ---
  for (int k = t; k < NBKT; k += 256) {
    const int c_ = hist[k];
    sbase[k] = c_ ? atomicAdd(&cursor[k], c_) : 0;
  }
  __syncthreads();

  // --- clustered record writes ---
#pragma unroll
  for (int j = 0; j < 28; ++j) {
    const int bk = w0[j] >> 22;
    const int pos = sbase[bk] + rank[j];
    if (pos < (bk + 1) * CAP)   // statistically unreachable guard
      sorted[pos] = make_uint2(w0[j], __float_as_uint(x[j]));
  }
}

// ---- bucket gather v2: in-LDS voxel sort, register accumulation ----
// block g: batch b=g>>8, voxels (g&255)*64..+64. 512 threads = 8 waves.
__global__ __launch_bounds__(512) void bucket_gather_kernel(
    const float* __restrict__ ctxT, const uint2* __restrict__ sorted,
    const int* __restrict__ cursor, float* __restrict__ out) {
  const int t = threadIdx.x;
  const int g = blockIdx.x;
  const int b = g >> 8;
  const int vox0 = (g & 255) * 64;

  __shared__ uint2 srec[CAP];        // 22528 B: voxel-sorted records
  __shared__ float tile[64][80];     // 20480 B: output tile
  __shared__ int shist[64], soff[64];

  if (t < 64) shist[t] = 0;
  __syncthreads();

  int cnt = cursor[g] - g * CAP;
  if (cnt > CAP) cnt = CAP;
  const uint2* rec = sorted + (size_t)g * CAP;

  // load <=6 records/thread to registers; histogram with rank (1.8K atomics)
  uint2 rr[6];
  int rk[6];
#pragma unroll
  for (int k = 0; k < 6; ++k) {
    const int idx = t + k * 512;
    rk[k] = -1;
    if (idx < cnt) {
      rr[k] = rec[idx];                                  // coalesced
      rk[k] = atomicAdd(&shist[(rr[k].x >> 16) & 63], 1);
    }
  }
  __syncthreads();

  // wave-0 exclusive prefix over 64 bins
  if (t < 64) {
    const int v = shist[t];
    int xx = v;
#pragma unroll
    for (int o = 1; o < 64; o <<= 1) {
      const int y = __shfl_up(xx, o, 64);
      if (t >= o) xx += y;
    }
    soff[t] = xx - v;
  }
  __syncthreads();

  // scatter records into voxel-sorted LDS order
#pragma unroll
  for (int k = 0; k < 6; ++k) {
    if (rk[k] >= 0) {
      const int v = (rr[k].x >> 16) & 63;
      srec[soff[v] + rk[k]] = rr[k];
    }
  }
  __syncthreads();

  // per-voxel register accumulation: wave w owns voxels w*8..w*8+8
  const int w = t >> 6;
  const int l = t & 63;
  for (int j = 0; j < 8; ++j) {
    const int v = w * 8 + j;
    const int s0 = soff[v];
    const int n = shist[v];
    float a0 = 0.0f, a1 = 0.0f;
    int k = 0;
    for (; k + 4 <= n; k += 4) {
      const uint2 ra = srec[s0 + k + 0];   // broadcast ds_read
      const uint2 rb = srec[s0 + k + 1];
      const uint2 rc = srec[s0 + k + 2];
      const uint2 rd = srec[s0 + k + 3];
      const float* wa = ctxT + (size_t)(ra.x & 0xFFFFu) * C;
      const float* wb = ctxT + (size_t)(rb.x & 0xFFFFu) * C;
      const float* wc = ctxT + (size_t)(rc.x & 0xFFFFu) * C;
      const float* wd = ctxT + (size_t)(rd.x & 0xFFFFu) * C;
      const float pa = __uint_as_float(ra.y);
      const float pb = __uint_as_float(rb.y);
      const float pc = __uint_as_float(rc.y);
      const float pd = __uint_as_float(rd.y);
      a0 += pa * wa[l];
      a0 += pb * wb[l];
      a0 += pc * wc[l];
      a0 += pd * wd[l];
      if (l < 16) {
        a1 += pa * wa[64 + l];
        a1 += pb * wb[64 + l];
        a1 += pc * wc[64 + l];
        a1 += pd * wd[64 + l];
      }
    }
    for (; k < n; ++k) {
      const uint2 ra = srec[s0 + k];
      const float* wa = ctxT + (size_t)(ra.x & 0xFFFFu) * C;
      const float pa = __uint_as_float(ra.y);
      a0 += pa * wa[l];
      if (l < 16) a1 += pa * wa[64 + l];
    }
    tile[v][l] = a0;                 // exclusive ownership: plain writes
    if (l < 16) tile[v][64 + l] = a1;
  }
  __syncthreads();

  // coalesced output write [b][c][vox0..vox0+64)
  const size_t ob = (size_t)b * C * NV + vox0;
#pragma unroll
  for (int i = 0; i < 10; ++i) {
    const int idx = i * 512 + t;
    const int c = idx >> 6;
    const int v = idx & 63;
    out[ob + (size_t)c * NV + v] = tile[v][c];
  }
}

// ---- fallback: direct channel-major atomics (out must be zeroed) ----
__global__ __launch_bounds__(256) void lift_splat_direct_kernel(
    const float* __restrict__ logits, const float* __restrict__ ctx,
    const int* __restrict__ gidx, float* __restrict__ out) {
  const int t = threadIdx.x;
  const int pix = blockIdx.x;
  const int hw = pix % HW;
  const int bn = pix / HW;
  const int b = bn / N;

  const float* lg = logits + (size_t)bn * DHW + hw;
  const int* gi = gidx + (size_t)bn * DHW + hw;
  const float* cx = ctx + (size_t)bn * (C * HW) + hw;

  __shared__ float s_prob[D];
  __shared__ float s_ctx[C];
  __shared__ int s_idx[D];
  __shared__ float red[256];

  float v = -3.0e38f;
  if (t < D) {
    v = lg[(size_t)t * HW];
    s_idx[t] = gi[(size_t)t * HW];
  }
  if (t < C) s_ctx[t] = cx[(size_t)t * HW];

  red[t] = v;
  __syncthreads();
#pragma unroll
  for (int s = 128; s >= 1; s >>= 1) {
    if (t < s) red[t] = fmaxf(red[t], red[t + s]);
    __syncthreads();
  }
  const float m = red[0];
  __syncthreads();

  const float e = (t < D) ? __expf(v - m) : 0.0f;
  red[t] = e;
  __syncthreads();
#pragma unroll
  for (int s = 128; s >= 1; s >>= 1) {
    if (t < s) red[t] += red[t + s];
    __syncthreads();
  }
  const float inv = 1.0f / red[0];
  if (t < D) s_prob[t] = e * inv;
  __syncthreads();

  for (int f = t; f < D * C; f += 256) {
    const int d = f / C;
    const int c = f - d * C;
    atomicAdd(&out[((size_t)(b * C + c)) * NV + s_idx[d]],
              s_prob[d] * s_ctx[c]);
  }
}

extern "C" void kernel_launch(void* const* d_in, const int* in_sizes, int n_in,
                              void* d_out, int out_size, void* d_ws,
                              size_t ws_size, hipStream_t stream) {
  const float* logits = (const float*)d_in[0];
  const float* ctx = (const float*)d_in[1];
  const int* gidx = (const int*)d_in[2];
  float* out = (float*)d_out;

  size_t off = 0;
  uint2* sorted = (uint2*)((char*)d_ws + off);
  off += (size_t)NBKT * CAP * sizeof(uint2);             // 11,534,336
  float* ctxT = (float*)((char*)d_ws + off);
  off += (size_t)NPIX * C * sizeof(float);               //  2,703,360
  int* cursor = (int*)((char*)d_ws + off);
  off += (size_t)NBKT * sizeof(int);                     // ~14.24 MB total

  if (ws_size >= off) {
    init_cursor_kernel<<<1, NBKT, 0, stream>>>(cursor);
    fused_scatter_kernel<<<NPIX / 64, 256, 0, stream>>>(logits, ctx, gidx,
                                                        ctxT, cursor, sorted);
    bucket_gather_kernel<<<NBKT, 512, 0, stream>>>(ctxT, sorted, cursor, out);
  } else {
    (void)hipMemsetAsync(d_out, 0, (size_t)out_size * sizeof(float), stream);
    lift_splat_direct_kernel<<<NPIX, 256, 0, stream>>>(logits, ctx, gidx, out);
  }
}